// Round 12
// baseline (381.390 us; speedup 1.0000x reference)
//
#include <hip/hip_runtime.h>
#include <hip/hip_bf16.h>
#include <stdint.h>

#define B_TOK 8192
#define DMODEL 512

typedef __attribute__((ext_vector_type(4))) float f32x4;
typedef __attribute__((ext_vector_type(8))) short bf16x8;
typedef __attribute__((ext_vector_type(4))) short bf16x4;
typedef __attribute__((ext_vector_type(2))) _Float16 f16x2;
typedef __attribute__((ext_vector_type(4))) _Float16 f16x4;
typedef __attribute__((ext_vector_type(8))) _Float16 f16x8;

__device__ __forceinline__ short f2bf(float f) {
    union { float f; uint32_t u; } v; v.f = f;
    uint32_t r = (v.u + 0x7fffu + ((v.u >> 16) & 1u)) >> 16;
    return (short)r;
}

__device__ __forceinline__ f16x2 pkrtz(float a, float b) {
    auto r = __builtin_amdgcn_cvt_pkrtz(a, b);
    union { decltype(r) i; f16x2 o; } u; u.i = r;
    return u.o;
}

__device__ __forceinline__ float sigm2(float x) {   // x pre-scaled by -log2e
    return __builtin_amdgcn_rcpf(1.0f + __builtin_amdgcn_exp2f(x));
}

#define NL2E (-1.44269504089f)
#define L2E  (1.44269504089f)

__device__ __forceinline__ f16x8 ldh(const float* __restrict__ p, float scl) {
    f32x4 a0 = *(const f32x4*)p * scl;
    f32x4 a1 = *(const f32x4*)(p + 4) * scl;
    f16x2 p0 = pkrtz(a0[0], a0[1]);
    f16x2 p1 = pkrtz(a0[2], a0[3]);
    f16x2 p2 = pkrtz(a1[0], a1[1]);
    f16x2 p3 = pkrtz(a1[2], a1[3]);
    return (f16x8){p0[0],p0[1],p1[0],p1[1],p2[0],p2[1],p3[0],p3[1]};
}

// ---- score-head machinery (swapped-operand MFMA pipeline) ----
struct ScoreW {
    f16x8 w1f[4][2];
    f32x4 b1f[4];
    f16x8 w2f[2];
    f32x4 b2v;
};

// fallback (no-ws) loader: from f32 weights, permute + convert in-wave
template <bool EXPS>
__device__ __forceinline__ void load_scorew(ScoreW& W,
    const float* __restrict__ w1p, const float* __restrict__ b1p,
    const float* __restrict__ w2p, const float* __restrict__ b2p,
    int tl, int g16)
{
    const float scl = EXPS ? NL2E : 1.0f;
    #pragma unroll
    for (int nt = 0; nt < 4; ++nt) {
        const int q  = nt >> 1;
        const int hi = (nt & 1) * 4;
        const int j  = q * 32 + (tl >> 2) * 8 + hi + (tl & 3);
        #pragma unroll
        for (int kk = 0; kk < 2; ++kk)
            W.w1f[nt][kk] = ldh(w1p + j * 64 + kk * 32 + g16 * 8, scl);
        W.b1f[nt] = *(const f32x4*)(b1p + q * 32 + g16 * 8 + hi) * scl;
    }
    #pragma unroll
    for (int q = 0; q < 2; ++q)
        W.w2f[q] = ldh(w2p + q * 32 + g16 * 8, 1.0f);
    const float b2 = b2p[0];
    f32x4 bb = {b2, b2, b2, b2};
    W.b2v = bb;
}

// pre-permuted f16 fragment loader: 14 coalesced loads, no converts.
__device__ __forceinline__ void load_scorew_pre(ScoreW& W,
    const _Float16* __restrict__ swf, const float* __restrict__ b1fp,
    const float* __restrict__ b2fp, int branch, int lane)
{
    #pragma unroll
    for (int nt = 0; nt < 4; ++nt)
        #pragma unroll
        for (int kk = 0; kk < 2; ++kk)
            W.w1f[nt][kk] = *(const f16x8*)(swf + ((size_t)(branch * 10 + nt * 2 + kk) * 64 + lane) * 8);
    W.w2f[0] = *(const f16x8*)(swf + ((size_t)(branch * 10 + 8) * 64 + lane) * 8);
    W.w2f[1] = *(const f16x8*)(swf + ((size_t)(branch * 10 + 9) * 64 + lane) * 8);
    #pragma unroll
    for (int nt = 0; nt < 4; ++nt)
        W.b1f[nt] = *(const f32x4*)(b1fp + ((size_t)(branch * 4 + nt) * 64 + lane) * 4);
    const float b2 = b2fp[branch];
    f32x4 bb = {b2, b2, b2, b2};
    W.b2v = bb;
}

template <bool POLY>
__device__ __forceinline__ f32x4 score16(const ScoreW& W, f16x8 xa0, f16x8 xa1)
{
    f32x4 acc1[4];
    __builtin_amdgcn_s_setprio(1);
    #pragma unroll
    for (int nt = 0; nt < 4; ++nt)
        acc1[nt] = __builtin_amdgcn_mfma_f32_16x16x32_f16(W.w1f[nt][0], xa0, W.b1f[nt], 0, 0, 0);
    #pragma unroll
    for (int nt = 0; nt < 4; ++nt)
        acc1[nt] = __builtin_amdgcn_mfma_f32_16x16x32_f16(W.w1f[nt][1], xa1, acc1[nt], 0, 0, 0);
    __builtin_amdgcn_s_setprio(0);

    f32x4 acc2a = W.b2v;
    f32x4 acc2b = {0.f, 0.f, 0.f, 0.f};
    #pragma unroll
    for (int q = 0; q < 2; ++q) {
        f16x8 sb;
        if constexpr (POLY) {
            const _Float16 c1 = (_Float16)0.25f;
            const _Float16 c2 = (_Float16)(-0.0208333f);
            const _Float16 c3 = (_Float16)0.00208333f;
            const _Float16 hf = (_Float16)0.5f;
            f16x2 h0 = pkrtz(acc1[2*q][0],   acc1[2*q][1]);
            f16x2 h1 = pkrtz(acc1[2*q][2],   acc1[2*q][3]);
            f16x2 h2 = pkrtz(acc1[2*q+1][0], acc1[2*q+1][1]);
            f16x2 h3 = pkrtz(acc1[2*q+1][2], acc1[2*q+1][3]);
            f16x8 hv = {h0[0],h0[1],h1[0],h1[1],h2[0],h2[1],h3[0],h3[1]};
            f16x8 C1 = {c1,c1,c1,c1,c1,c1,c1,c1};
            f16x8 C2 = {c2,c2,c2,c2,c2,c2,c2,c2};
            f16x8 C3 = {c3,c3,c3,c3,c3,c3,c3,c3};
            f16x8 HF = {hf,hf,hf,hf,hf,hf,hf,hf};
            f16x8 hh = hv * hv;
            f16x8 u  = hh * C3 + C2;
            f16x8 v  = hh * u  + C1;
            sb       = hv * v  + HF;
        } else {
            f16x2 s0 = pkrtz(sigm2(acc1[2*q][0]),   sigm2(acc1[2*q][1]));
            f16x2 s1 = pkrtz(sigm2(acc1[2*q][2]),   sigm2(acc1[2*q][3]));
            f16x2 s2 = pkrtz(sigm2(acc1[2*q+1][0]), sigm2(acc1[2*q+1][1]));
            f16x2 s3 = pkrtz(sigm2(acc1[2*q+1][2]), sigm2(acc1[2*q+1][3]));
            sb = (f16x8){s0[0],s0[1],s1[0],s1[1],s2[0],s2[1],s3[0],s3[1]};
        }
        __builtin_amdgcn_s_setprio(1);
        if (q == 0)
            acc2a = __builtin_amdgcn_mfma_f32_16x16x32_f16(W.w2f[0], sb, acc2a, 0, 0, 0);
        else
            acc2b = __builtin_amdgcn_mfma_f32_16x16x32_f16(W.w2f[1], sb, acc2b, 0, 0, 0);
        __builtin_amdgcn_s_setprio(0);
    }
    return acc2a + acc2b;
}

// =====================================================================
// Kernel 1 (r12): 8 waves x 4 tokens. r11 foundation (LDS-staged f16
// inputs, pipelined pair loop, poly sigmoid, pre-permuted weights,
// setprio) with pairs split across 8 waves (L:5/5/5/5, S:4/4/4/3) ->
// per-wave serial chain halved, resident-wave ceiling doubled (24/CU).
// r6's 8-wave failure mode (per-wave weight permute+convert tax) is
// eliminated by load_scorew_pre (14 coalesced loads).
// =====================================================================
template <bool WSB>
__global__ __launch_bounds__(512, 4) void fused_att(
    const float* __restrict__ user, const float* __restrict__ mood,
    const float* __restrict__ genre,
    const float* __restrict__ lw1,  const float* __restrict__ lb1,
    const float* __restrict__ lw2,  const float* __restrict__ lb2,
    const float* __restrict__ sw1,  const float* __restrict__ sb1,
    const float* __restrict__ sw2,  const float* __restrict__ sb2,
    const float* __restrict__ zlw1, const float* __restrict__ zlb1,
    const float* __restrict__ zlw2, const float* __restrict__ zlb2,
    const float* __restrict__ zsw1, const float* __restrict__ zsb1,
    const float* __restrict__ zsw2, const float* __restrict__ zsb2,
    const _Float16* __restrict__ swf, const float* __restrict__ b1fp,
    const float* __restrict__ b2fp,
    float* __restrict__ fout, short* __restrict__ bout)
{
    // input: 12 arrays x 32 rows x 64 f16 (128B rows, XOR-swizzled) = 49152B
    // overlay after pair loop: att [8][32][80] f16 (40960B) + rsc [2][32] f32
    __shared__ __attribute__((aligned(16))) unsigned char smraw[12 * 32 * 128];
    _Float16* att = (_Float16*)smraw;              // [8][32][80]
    float*    rsc = (float*)(smraw + 40960);       // [2][32]

    const int tid  = threadIdx.x;
    const int lane = tid & 63;
    const int wv   = tid >> 6;    // 0..7
    const int tl   = lane & 15;
    const int g16  = lane >> 4;
    const int wg   = blockIdx.x;  // tokens [4*wg, 4*wg+4)

    // ---------------- stage inputs fp32 -> f16 LDS (512 threads) ------
    {
        const int r  = tid >> 4;             // 0..31
        const int k4 = (tid & 15) << 2;
        const int dst_off = r * 128 + ((k4 * 2) ^ ((r & 7) << 4));
        const size_t src_off = (size_t)wg * 2048 + (size_t)r * 64 + k4;
        #pragma unroll
        for (int a = 0; a < 12; ++a) {
            const float* src; float scl;
            if (a < 4)      { src = user  + (size_t)a       * (B_TOK * DMODEL); scl = 0.125f; }
            else if (a < 9) { src = genre + (size_t)(a - 4) * (B_TOK * DMODEL); scl = 1.0f;  }
            else            { src = mood  + (size_t)(a - 9) * (B_TOK * DMODEL); scl = 0.125f; }
            f32x4 v = *(const f32x4*)(src + src_off) * scl;
            f16x2 lo = pkrtz(v[0], v[1]);
            f16x2 hi = pkrtz(v[2], v[3]);
            f16x4 b = {lo[0], lo[1], hi[0], hi[1]};
            *(f16x4*)(smraw + a * 4096 + dst_off) = b;
        }
    }
    __syncthreads();

    // ---------------- per-wave weights ----------------
    ScoreW W;
    if constexpr (WSB) {
        load_scorew_pre(W, swf, b1fp, b2fp, (wv < 4) ? 0 : 1, lane);
    } else {
        if (wv < 4) load_scorew<false>(W, lw1, lb1, lw2, lb2, tl, g16);
        else        load_scorew<false>(W, sw1, sb1, sw2, sb2, tl, g16);
    }

    // waves 0-3: L pairs 5/5/5/5; waves 4-7: S pairs 4/4/4/3
    int pstart, pcount, sbase;
    if (wv < 4) { pstart = 5 * wv;       pcount = 5;                  sbase = 0; }
    else        { pstart = 4 * (wv - 4); pcount = (wv == 7) ? 3 : 4;  sbase = 9; }

    int aA = sbase + pstart / 5;
    int aB = 4 + pstart % 5;

    f16x8 attA0 = {0,0,0,0,0,0,0,0}, attA1 = {0,0,0,0,0,0,0,0};
    f16x8 attB0 = {0,0,0,0,0,0,0,0}, attB1 = {0,0,0,0,0,0,0,0};

    const unsigned char* lbase = smraw;
    const int rowbA = tl * 128;
    const int rowbB = (16 + tl) * 128;
    const int swz   = (tl & 7) << 4;
    const int ko2   = g16 * 16;
    const int o0 = ko2 ^ swz;
    const int o1 = (ko2 + 64) ^ swz;

    auto rd = [&](int arr, int rowb, int off) -> f16x8 {
        return *(const f16x8*)(lbase + arr * 4096 + rowb + off);
    };

    // software-pipelined pair loop
    f16x8 uA0 = rd(aA, rowbA, o0), uA1 = rd(aA, rowbA, o1);
    f16x8 uB0 = rd(aA, rowbB, o0), uB1 = rd(aA, rowbB, o1);
    f16x8 gA0 = rd(aB, rowbA, o0), gA1 = rd(aB, rowbA, o1);
    f16x8 gB0 = rd(aB, rowbB, o0), gB1 = rd(aB, rowbB, o1);

    for (int pi = 0; pi < pcount; ++pi) {
        f16x8 xaA0 = uA0 * gA0, xaA1 = uA1 * gA1;
        f16x8 xaB0 = uB0 * gB0, xaB1 = uB1 * gB1;

        f16x8 ngA0 = gA0, ngA1 = gA1, ngB0 = gB0, ngB1 = gB1;
        if (pi + 1 < pcount) {                 // wave-uniform branch
            int nB = aB + 1;
            if (nB == 9) {
                nB = 4; ++aA;
                uA0 = rd(aA, rowbA, o0); uA1 = rd(aA, rowbA, o1);
                uB0 = rd(aA, rowbB, o0); uB1 = rd(aA, rowbB, o1);
            }
            aB = nB;
            ngA0 = rd(aB, rowbA, o0); ngA1 = rd(aB, rowbA, o1);
            ngB0 = rd(aB, rowbB, o0); ngB1 = rd(aB, rowbB, o1);
        }

        f32x4 scA = score16<true>(W, xaA0, xaA1);
        f32x4 scB = score16<true>(W, xaB0, xaB1);

        _Float16 hA = (_Float16)scA[0];
        _Float16 hB = (_Float16)scB[0];
        f16x8 svA = {hA,hA,hA,hA,hA,hA,hA,hA};
        f16x8 svB = {hB,hB,hB,hB,hB,hB,hB,hB};
        attA0 += svA * xaA0;
        attA1 += svA * xaA1;
        attB0 += svB * xaB0;
        attB1 += svB * xaB1;

        gA0 = ngA0; gA1 = ngA1; gB0 = ngB0; gB1 = ngB1;
    }

    __syncthreads();   // all waves done READING inputs before overlay write

    // ---------------- write att partials (f16, overlay) ----------------
    *(f16x8*)(att + (wv * 32 + tl) * 80 + g16 * 8)           = attA0;
    *(f16x8*)(att + (wv * 32 + tl) * 80 + 32 + g16 * 8)      = attA1;
    *(f16x8*)(att + (wv * 32 + 16 + tl) * 80 + g16 * 8)      = attB0;
    *(f16x8*)(att + (wv * 32 + 16 + tl) * 80 + 32 + g16 * 8) = attB1;
    __syncthreads();

    // ---------------- gate scores rl / rs (exact exp2 path) -----------
    if (wv < 2) {
        ScoreW ZW;
        if constexpr (WSB) {
            load_scorew_pre(ZW, swf, b1fp, b2fp, (wv == 0) ? 2 : 3, lane);
        } else {
            if (wv == 0) load_scorew<true>(ZW, zlw1, zlb1, zlw2, zlb2, tl, g16);
            else         load_scorew<true>(ZW, zsw1, zsb1, zsw2, zsb2, tl, g16);
        }
        const int wb0 = wv * 4;   // wv0 sums L waves 0-3; wv1 sums S waves 4-7
        #pragma unroll
        for (int g = 0; g < 2; ++g) {
            const int r = g * 16 + tl;
            f16x8 za0 = *(const f16x8*)(att + ((wb0 + 0) * 32 + r) * 80 + g16 * 8)
                      + *(const f16x8*)(att + ((wb0 + 1) * 32 + r) * 80 + g16 * 8)
                      + *(const f16x8*)(att + ((wb0 + 2) * 32 + r) * 80 + g16 * 8)
                      + *(const f16x8*)(att + ((wb0 + 3) * 32 + r) * 80 + g16 * 8);
            f16x8 za1 = *(const f16x8*)(att + ((wb0 + 0) * 32 + r) * 80 + 32 + g16 * 8)
                      + *(const f16x8*)(att + ((wb0 + 1) * 32 + r) * 80 + 32 + g16 * 8)
                      + *(const f16x8*)(att + ((wb0 + 2) * 32 + r) * 80 + 32 + g16 * 8)
                      + *(const f16x8*)(att + ((wb0 + 3) * 32 + r) * 80 + 32 + g16 * 8);
            f32x4 rz = score16<false>(ZW, za0, za1);
            if (g16 == 0) rsc[wv * 32 + r] = rz[0];
        }
    }
    __syncthreads();

    // ---------------- mix + store (512 threads, one pass) -------------
    {
        const int r  = tid >> 4;             // 0..31
        const int k4 = (tid & 15) << 2;
        f16x4 Lh = {0,0,0,0}, Sh = {0,0,0,0};
        #pragma unroll
        for (int b = 0; b < 4; ++b) {
            Lh += *(const f16x4*)(att + ((b + 0) * 32 + r) * 80 + k4);
            Sh += *(const f16x4*)(att + ((b + 4) * 32 + r) * 80 + k4);
        }
        const float rl = rsc[r], rs = rsc[32 + r];
        const float r0 = __builtin_amdgcn_rcpf(1.0f + __builtin_amdgcn_exp2f((rs - rl) * L2E));
        float o[4];
        #pragma unroll
        for (int i = 0; i < 4; ++i) {
            const float Lf = (float)Lh[i], Sf = (float)Sh[i];
            o[i] = Sf + (Lf - Sf) * r0;
        }
        const size_t base = (size_t)wg * 2048 + (size_t)r * 64 + k4;
        if constexpr (WSB) {
            bf16x4 b = {f2bf(o[0]), f2bf(o[1]), f2bf(o[2]), f2bf(o[3])};
            *(bf16x4*)(bout + base) = b;
        } else {
            f32x4 mx = {o[0], o[1], o[2], o[3]};
            *(f32x4*)(fout + base) = mx;
        }
    }
}

// =====================================================================
// Kernel 0a: lin_w fp32 -> bf16 into workspace
// =====================================================================
__global__ __launch_bounds__(256) void conv_w(const float* __restrict__ w,
                                              short* __restrict__ o)
{
    const size_t i = ((size_t)blockIdx.x * 256 + threadIdx.x) * 4;
    f32x4 v = *(const f32x4*)(w + i);
    bf16x4 b;
    b[0] = f2bf(v[0]); b[1] = f2bf(v[1]); b[2] = f2bf(v[2]); b[3] = f2bf(v[3]);
    *(bf16x4*)(o + i) = b;
}

// =====================================================================
// Kernel 0b: score weights -> pre-permuted f16 fragments in ws.
// =====================================================================
__global__ __launch_bounds__(256) void conv_sw(
    const float* __restrict__ lw1,  const float* __restrict__ lb1,
    const float* __restrict__ lw2,  const float* __restrict__ lb2,
    const float* __restrict__ sw1,  const float* __restrict__ sb1,
    const float* __restrict__ sw2,  const float* __restrict__ sb2,
    const float* __restrict__ zlw1, const float* __restrict__ zlb1,
    const float* __restrict__ zlw2, const float* __restrict__ zlb2,
    const float* __restrict__ zsw1, const float* __restrict__ zsb1,
    const float* __restrict__ zsw2, const float* __restrict__ zsb2,
    _Float16* __restrict__ swf, float* __restrict__ b1f, float* __restrict__ b2f)
{
    const int blk = blockIdx.x, tid = threadIdx.x;
    if (blk < 80) {
        const int idx = blk * 256 + tid;          // 0..20479
        const int e = idx & 7;
        int t = idx >> 3;
        const int lane = t & 63; t >>= 6;
        const int f = t % 10;
        const int branch = t / 10;
        const int tl = lane & 15, g16 = lane >> 4;
        const float* w1p = (branch == 0) ? lw1 : (branch == 1) ? sw1 : (branch == 2) ? zlw1 : zsw1;
        const float* w2p = (branch == 0) ? lw2 : (branch == 1) ? sw2 : (branch == 2) ? zlw2 : zsw2;
        float val;
        if (f < 8) {
            const int nt = f >> 1, kk = f & 1;
            const int q = nt >> 1, hi = (nt & 1) * 4;
            const int j = q * 32 + (tl >> 2) * 8 + hi + (tl & 3);
            val = w1p[j * 64 + kk * 32 + g16 * 8 + e];
            if (branch >= 2) val *= NL2E;
        } else {
            const int q = f - 8;
            val = w2p[q * 32 + g16 * 8 + e];
        }
        swf[idx] = (_Float16)val;
    } else {
        const int idx = (blk - 80) * 256 + tid;   // 0..1023
        const int branch = idx >> 8, nt = (idx >> 6) & 3, lane = idx & 63;
        const int q = nt >> 1, hi = (nt & 1) * 4, g16 = lane >> 4;
        const float* b1p = (branch == 0) ? lb1 : (branch == 1) ? sb1 : (branch == 2) ? zlb1 : zsb1;
        const float scl = (branch >= 2) ? NL2E : 1.0f;
        #pragma unroll
        for (int c = 0; c < 4; ++c)
            b1f[idx * 4 + c] = b1p[q * 32 + g16 * 8 + hi + c] * scl;
        if (blk == 80 && tid < 4) {
            const float* b2p = (tid == 0) ? lb2 : (tid == 1) ? sb2 : (tid == 2) ? zlb2 : zsb2;
            b2f[tid] = b2p[0];
        }
    }
}

// =====================================================================
// Kernel 2 (ws path): C = mix_bf16 @ linw_bf16^T + linb.
// =====================================================================
__global__ __launch_bounds__(256, 2) void final_gemm_ws(
    const short* __restrict__ A, const short* __restrict__ Bw,
    const float* __restrict__ bias, float* __restrict__ C)
{
    __shared__ __attribute__((aligned(16))) short lA[64 * 64];
    __shared__ __attribute__((aligned(16))) short lB[128 * 64];

    const int tid  = threadIdx.x;
    const int lane = tid & 63;
    const int wv   = tid >> 6;
    const int tl   = lane & 15;
    const int g16  = lane >> 4;
    const int wr   = wv >> 1;
    const int wc   = wv & 1;
    const int bm   = blockIdx.x & 127;
    const int bn   = blockIdx.x >> 7;
    const int m0   = bm * 64, n0 = bn * 128;

    f32x4 acc[2][4];
    #pragma unroll
    for (int mt = 0; mt < 2; ++mt)
        #pragma unroll
        for (int nt = 0; nt < 4; ++nt) { f32x4 z = {0.f,0.f,0.f,0.f}; acc[mt][nt] = z; }

    bf16x8 ra[2], rb[4];
    auto LD = [&](int ks) {
        #pragma unroll
        for (int i = 0; i < 2; ++i) {
            const int c = tid + i * 256;
            ra[i] = *(const bf16x8*)(A + (size_t)(m0 + (c >> 3)) * 512 + ks * 64 + (c & 7) * 8);
        }
        #pragma unroll
        for (int i = 0; i < 4; ++i) {
            const int c = tid + i * 256;
            rb[i] = *(const bf16x8*)(Bw + (size_t)(n0 + (c >> 3)) * 512 + ks * 64 + (c & 7) * 8);
        }
    };

    LD(0);
    for (int ks = 0; ks < 8; ++ks) {
        __syncthreads();
        #pragma unroll
        for (int i = 0; i < 2; ++i) {
            const int c = tid + i * 256, row = c >> 3;
            *(bf16x8*)(lA + row * 64 + ((c & 7) ^ (row & 7)) * 8) = ra[i];
        }
        #pragma unroll
        for (int i = 0; i < 4; ++i) {
            const int c = tid + i * 256, row = c >> 3;
            *(bf16x8*)(lB + row * 64 + ((c & 7) ^ (row & 7)) * 8) = rb[i];
        }
        __syncthreads();
        if (ks < 7) LD(ks + 1);
        #pragma unroll
        for (int kk = 0; kk < 2; ++kk) {
            bf16x8 af[2], bfr[4];
            #pragma unroll
            for (int mt = 0; mt < 2; ++mt) {
                const int row = wr * 32 + mt * 16 + tl;
                af[mt] = *(const bf16x8*)(lA + row * 64 + ((kk * 4 + g16) ^ (row & 7)) * 8);
            }
            #pragma unroll
            for (int nt = 0; nt < 4; ++nt) {
                const int row = wc * 64 + nt * 16 + tl;
                bfr[nt] = *(const bf16x8*)(lB + row * 64 + ((kk * 4 + g16) ^ (row & 7)) * 8);
            }
            #pragma unroll
            for (int mt = 0; mt < 2; ++mt)
                #pragma unroll
                for (int nt = 0; nt < 4; ++nt)
                    acc[mt][nt] = __builtin_amdgcn_mfma_f32_16x16x32_bf16(af[mt], bfr[nt], acc[mt][nt], 0, 0, 0);
        }
    }

    #pragma unroll
    for (int nt = 0; nt < 4; ++nt) {
        const int n = n0 + wc * 64 + nt * 16 + tl;
        const float bv = bias[n];
        #pragma unroll
        for (int mt = 0; mt < 2; ++mt) {
            #pragma unroll
            for (int r = 0; r < 4; ++r) {
                C[(size_t)(m0 + wr * 32 + mt * 16 + g16 * 4 + r) * 512 + n] = acc[mt][nt][r] + bv;
            }
        }
    }
}

// =====================================================================
// Fallback (no ws): in-place GEMM on d_out
// =====================================================================
__global__ __launch_bounds__(256, 2) void final_gemm_ip(
    const float* __restrict__ linw, const float* __restrict__ linb, float* io)
{
    const int tid  = threadIdx.x;
    const int lane = tid & 63;
    const int wv   = tid >> 6;
    const int tl   = lane & 15;
    const int g16  = lane >> 4;
    const int row0 = blockIdx.x * 64 + wv * 16;

    f32x4 acc[32];
    #pragma unroll
    for (int nt = 0; nt < 32; ++nt) { f32x4 z = {0.f,0.f,0.f,0.f}; acc[nt] = z; }

    for (int ks = 0; ks < 16; ++ks) {
        const int k0 = ks * 32 + g16 * 8;
        const float* ar = io + (size_t)(row0 + tl) * 512 + k0;
        f32x4 a0 = *(const f32x4*)ar;
        f32x4 a1 = *(const f32x4*)(ar + 4);
        bf16x8 af;
        af[0]=f2bf(a0[0]); af[1]=f2bf(a0[1]); af[2]=f2bf(a0[2]); af[3]=f2bf(a0[3]);
        af[4]=f2bf(a1[0]); af[5]=f2bf(a1[1]); af[6]=f2bf(a1[2]); af[7]=f2bf(a1[3]);
        #pragma unroll
        for (int nt = 0; nt < 32; ++nt) {
            const int n = nt * 16 + tl;
            const float* br = linw + (size_t)n * 512 + k0;
            f32x4 b0 = *(const f32x4*)br;
            f32x4 b1 = *(const f32x4*)(br + 4);
            bf16x8 bv;
            bv[0]=f2bf(b0[0]); bv[1]=f2bf(b0[1]); bv[2]=f2bf(b0[2]); bv[3]=f2bf(b0[3]);
            bv[4]=f2bf(b1[0]); bv[5]=f2bf(b1[1]); bv[6]=f2bf(b1[2]); bv[7]=f2bf(b1[3]);
            acc[nt] = __builtin_amdgcn_mfma_f32_16x16x32_bf16(af, bv, acc[nt], 0, 0, 0);
        }
    }

    #pragma unroll
    for (int nt = 0; nt < 32; ++nt) {
        const int n = nt * 16 + tl;
        const float lb = linb[n];
        #pragma unroll
        for (int r = 0; r < 4; ++r)
            io[(size_t)(row0 + g16 * 4 + r) * 512 + n] = acc[nt][r] + lb;
    }
}

// =====================================================================
extern "C" void kernel_launch(void* const* d_in, const int* in_sizes, int n_in,
                              void* d_out, int out_size, void* d_ws, size_t ws_size,
                              hipStream_t stream)
{
    const float* user = (const float*)d_in[0];
    const float* mood = (const float*)d_in[1];
    const float* genre= (const float*)d_in[2];
    const float* lw1  = (const float*)d_in[3];
    const float* lb1  = (const float*)d_in[4];
    const float* lw2  = (const float*)d_in[5];
    const float* lb2  = (const float*)d_in[6];
    const float* sw1  = (const float*)d_in[7];
    const float* sb1  = (const float*)d_in[8];
    const float* sw2  = (const float*)d_in[9];
    const float* sb2  = (const float*)d_in[10];
    const float* zlw1 = (const float*)d_in[11];
    const float* zlb1 = (const float*)d_in[12];
    const float* zlw2 = (const float*)d_in[13];
    const float* zlb2 = (const float*)d_in[14];
    const float* zsw1 = (const float*)d_in[15];
    const float* zsb1 = (const float*)d_in[16];
    const float* zsw2 = (const float*)d_in[17];
    const float* zsb2 = (const float*)d_in[18];
    const float* linw = (const float*)d_in[19];
    const float* linb = (const float*)d_in[20];
    float* out = (float*)d_out;

    const size_t SWF_ELTS = (size_t)4 * 10 * 64 * 8;   // 20480 f16
    const size_t B1F_ELTS = (size_t)4 * 4 * 64 * 4;    // 4096 f32
    const size_t WNEED = (size_t)512 * 512 * 2 + (size_t)B_TOK * 512 * 2
                       + SWF_ELTS * 2 + (B1F_ELTS + 4) * 4;

    if (ws_size >= WNEED) {
        short*     wb   = (short*)d_ws;
        short*     mixb = wb + 512 * 512;
        _Float16*  swf  = (_Float16*)(mixb + (size_t)B_TOK * 512);
        float*     b1f  = (float*)(swf + SWF_ELTS);
        float*     b2f  = b1f + B1F_ELTS;

        conv_w<<<256, 256, 0, stream>>>(linw, wb);
        conv_sw<<<84, 256, 0, stream>>>(lw1, lb1, lw2, lb2, sw1, sb1, sw2, sb2,
                                        zlw1, zlb1, zlw2, zlb2, zsw1, zsb1, zsw2, zsb2,
                                        swf, b1f, b2f);
        fused_att<true><<<B_TOK / 4, 512, 0, stream>>>(
            user, mood, genre,
            lw1, lb1, lw2, lb2, sw1, sb1, sw2, sb2,
            zlw1, zlb1, zlw2, zlb2, zsw1, zsb1, zsw2, zsb2,
            swf, b1f, b2f, nullptr, mixb);
        final_gemm_ws<<<512, 256, 0, stream>>>(mixb, wb, linb, out);
    } else {
        fused_att<false><<<B_TOK / 4, 512, 0, stream>>>(
            user, mood, genre,
            lw1, lb1, lw2, lb2, sw1, sb1, sw2, sb2,
            zlw1, zlb1, zlw2, zlb2, zsw1, zsb1, zsw2, zsb2,
            nullptr, nullptr, nullptr, out, nullptr);
        final_gemm_ip<<<B_TOK / 64, 256, 0, stream>>>(linw, linb, out);
    }
}

// Round 13
// 95.172 us; speedup vs baseline: 4.0074x; 4.0074x over previous
//
#include <hip/hip_runtime.h>
#include <hip/hip_bf16.h>
#include <stdint.h>

#define B_TOK 8192
#define DMODEL 512

typedef __attribute__((ext_vector_type(4))) float f32x4;
typedef __attribute__((ext_vector_type(8))) short bf16x8;
typedef __attribute__((ext_vector_type(4))) short bf16x4;
typedef __attribute__((ext_vector_type(2))) _Float16 f16x2;
typedef __attribute__((ext_vector_type(4))) _Float16 f16x4;
typedef __attribute__((ext_vector_type(8))) _Float16 f16x8;

__device__ __forceinline__ short f2bf(float f) {
    union { float f; uint32_t u; } v; v.f = f;
    uint32_t r = (v.u + 0x7fffu + ((v.u >> 16) & 1u)) >> 16;
    return (short)r;
}

__device__ __forceinline__ f16x2 pkrtz(float a, float b) {
    auto r = __builtin_amdgcn_cvt_pkrtz(a, b);
    union { decltype(r) i; f16x2 o; } u; u.i = r;
    return u.o;
}

__device__ __forceinline__ float sigm2(float x) {   // x pre-scaled by -log2e
    return __builtin_amdgcn_rcpf(1.0f + __builtin_amdgcn_exp2f(x));
}

#define NL2E (-1.44269504089f)
#define L2E  (1.44269504089f)

__device__ __forceinline__ f16x8 ldh(const float* __restrict__ p, float scl) {
    f32x4 a0 = *(const f32x4*)p * scl;
    f32x4 a1 = *(const f32x4*)(p + 4) * scl;
    f16x2 p0 = pkrtz(a0[0], a0[1]);
    f16x2 p1 = pkrtz(a0[2], a0[3]);
    f16x2 p2 = pkrtz(a1[0], a1[1]);
    f16x2 p3 = pkrtz(a1[2], a1[3]);
    return (f16x8){p0[0],p0[1],p1[0],p1[1],p2[0],p2[1],p3[0],p3[1]};
}

// ---- score-head machinery (swapped-operand MFMA pipeline) ----
struct ScoreW {
    f16x8 w1f[4][2];
    f32x4 b1f[4];
    f16x8 w2f[2];
    f32x4 b2v;
};

// fallback (no-ws) loader: from f32 weights, permute + convert in-wave
template <bool EXPS>
__device__ __forceinline__ void load_scorew(ScoreW& W,
    const float* __restrict__ w1p, const float* __restrict__ b1p,
    const float* __restrict__ w2p, const float* __restrict__ b2p,
    int tl, int g16)
{
    const float scl = EXPS ? NL2E : 1.0f;
    #pragma unroll
    for (int nt = 0; nt < 4; ++nt) {
        const int q  = nt >> 1;
        const int hi = (nt & 1) * 4;
        const int j  = q * 32 + (tl >> 2) * 8 + hi + (tl & 3);
        #pragma unroll
        for (int kk = 0; kk < 2; ++kk)
            W.w1f[nt][kk] = ldh(w1p + j * 64 + kk * 32 + g16 * 8, scl);
        W.b1f[nt] = *(const f32x4*)(b1p + q * 32 + g16 * 8 + hi) * scl;
    }
    #pragma unroll
    for (int q = 0; q < 2; ++q)
        W.w2f[q] = ldh(w2p + q * 32 + g16 * 8, 1.0f);
    const float b2 = b2p[0];
    f32x4 bb = {b2, b2, b2, b2};
    W.b2v = bb;
}

// pre-permuted f16 fragment loader: 14 coalesced loads, no converts.
__device__ __forceinline__ void load_scorew_pre(ScoreW& W,
    const _Float16* __restrict__ swf, const float* __restrict__ b1fp,
    const float* __restrict__ b2fp, int branch, int lane)
{
    #pragma unroll
    for (int nt = 0; nt < 4; ++nt)
        #pragma unroll
        for (int kk = 0; kk < 2; ++kk)
            W.w1f[nt][kk] = *(const f16x8*)(swf + ((size_t)(branch * 10 + nt * 2 + kk) * 64 + lane) * 8);
    W.w2f[0] = *(const f16x8*)(swf + ((size_t)(branch * 10 + 8) * 64 + lane) * 8);
    W.w2f[1] = *(const f16x8*)(swf + ((size_t)(branch * 10 + 9) * 64 + lane) * 8);
    #pragma unroll
    for (int nt = 0; nt < 4; ++nt)
        W.b1f[nt] = *(const f32x4*)(b1fp + ((size_t)(branch * 4 + nt) * 64 + lane) * 4);
    const float b2 = b2fp[branch];
    f32x4 bb = {b2, b2, b2, b2};
    W.b2v = bb;
}

template <bool POLY>
__device__ __forceinline__ f32x4 score16(const ScoreW& W, f16x8 xa0, f16x8 xa1)
{
    f32x4 acc1[4];
    __builtin_amdgcn_s_setprio(1);
    #pragma unroll
    for (int nt = 0; nt < 4; ++nt)
        acc1[nt] = __builtin_amdgcn_mfma_f32_16x16x32_f16(W.w1f[nt][0], xa0, W.b1f[nt], 0, 0, 0);
    #pragma unroll
    for (int nt = 0; nt < 4; ++nt)
        acc1[nt] = __builtin_amdgcn_mfma_f32_16x16x32_f16(W.w1f[nt][1], xa1, acc1[nt], 0, 0, 0);
    __builtin_amdgcn_s_setprio(0);

    f32x4 acc2a = W.b2v;
    f32x4 acc2b = {0.f, 0.f, 0.f, 0.f};
    #pragma unroll
    for (int q = 0; q < 2; ++q) {
        f16x8 sb;
        if constexpr (POLY) {
            const _Float16 c1 = (_Float16)0.25f;
            const _Float16 c2 = (_Float16)(-0.0208333f);
            const _Float16 c3 = (_Float16)0.00208333f;
            const _Float16 hf = (_Float16)0.5f;
            f16x2 h0 = pkrtz(acc1[2*q][0],   acc1[2*q][1]);
            f16x2 h1 = pkrtz(acc1[2*q][2],   acc1[2*q][3]);
            f16x2 h2 = pkrtz(acc1[2*q+1][0], acc1[2*q+1][1]);
            f16x2 h3 = pkrtz(acc1[2*q+1][2], acc1[2*q+1][3]);
            f16x8 hv = {h0[0],h0[1],h1[0],h1[1],h2[0],h2[1],h3[0],h3[1]};
            f16x8 C1 = {c1,c1,c1,c1,c1,c1,c1,c1};
            f16x8 C2 = {c2,c2,c2,c2,c2,c2,c2,c2};
            f16x8 C3 = {c3,c3,c3,c3,c3,c3,c3,c3};
            f16x8 HF = {hf,hf,hf,hf,hf,hf,hf,hf};
            f16x8 hh = hv * hv;
            f16x8 u  = hh * C3 + C2;
            f16x8 v  = hh * u  + C1;
            sb       = hv * v  + HF;
        } else {
            f16x2 s0 = pkrtz(sigm2(acc1[2*q][0]),   sigm2(acc1[2*q][1]));
            f16x2 s1 = pkrtz(sigm2(acc1[2*q][2]),   sigm2(acc1[2*q][3]));
            f16x2 s2 = pkrtz(sigm2(acc1[2*q+1][0]), sigm2(acc1[2*q+1][1]));
            f16x2 s3 = pkrtz(sigm2(acc1[2*q+1][2]), sigm2(acc1[2*q+1][3]));
            sb = (f16x8){s0[0],s0[1],s1[0],s1[1],s2[0],s2[1],s3[0],s3[1]};
        }
        __builtin_amdgcn_s_setprio(1);
        if (q == 0)
            acc2a = __builtin_amdgcn_mfma_f32_16x16x32_f16(W.w2f[0], sb, acc2a, 0, 0, 0);
        else
            acc2b = __builtin_amdgcn_mfma_f32_16x16x32_f16(W.w2f[1], sb, acc2b, 0, 0, 0);
        __builtin_amdgcn_s_setprio(0);
    }
    return acc2a + acc2b;
}

// =====================================================================
// Kernel 1 (r13): r12 structure (8 waves x 4 tokens, pipelined pair
// loop, pre-permuted weights) with the spill fixed: launch_bounds
// min-waves 4 -> 2, giving the allocator a 256-VGPR budget (working
// set ~150). r12's 128-VGPR cap spilled ScoreW (FETCH 744MB, WRITE
// 655MB); occupancy DID rise to 41% -- the lever works, spill buried it.
// =====================================================================
template <bool WSB>
__global__ __launch_bounds__(512, 2) void fused_att(
    const float* __restrict__ user, const float* __restrict__ mood,
    const float* __restrict__ genre,
    const float* __restrict__ lw1,  const float* __restrict__ lb1,
    const float* __restrict__ lw2,  const float* __restrict__ lb2,
    const float* __restrict__ sw1,  const float* __restrict__ sb1,
    const float* __restrict__ sw2,  const float* __restrict__ sb2,
    const float* __restrict__ zlw1, const float* __restrict__ zlb1,
    const float* __restrict__ zlw2, const float* __restrict__ zlb2,
    const float* __restrict__ zsw1, const float* __restrict__ zsb1,
    const float* __restrict__ zsw2, const float* __restrict__ zsb2,
    const _Float16* __restrict__ swf, const float* __restrict__ b1fp,
    const float* __restrict__ b2fp,
    float* __restrict__ fout, short* __restrict__ bout)
{
    // input: 12 arrays x 32 rows x 64 f16 (128B rows, XOR-swizzled) = 49152B
    // overlay after pair loop: att [8][32][80] f16 (40960B) + rsc [2][32] f32
    __shared__ __attribute__((aligned(16))) unsigned char smraw[12 * 32 * 128];
    _Float16* att = (_Float16*)smraw;              // [8][32][80]
    float*    rsc = (float*)(smraw + 40960);       // [2][32]

    const int tid  = threadIdx.x;
    const int lane = tid & 63;
    const int wv   = tid >> 6;    // 0..7
    const int tl   = lane & 15;
    const int g16  = lane >> 4;
    const int wg   = blockIdx.x;  // tokens [4*wg, 4*wg+4)

    // ---------------- stage inputs fp32 -> f16 LDS (512 threads) ------
    {
        const int r  = tid >> 4;             // 0..31
        const int k4 = (tid & 15) << 2;
        const int dst_off = r * 128 + ((k4 * 2) ^ ((r & 7) << 4));
        const size_t src_off = (size_t)wg * 2048 + (size_t)r * 64 + k4;
        #pragma unroll
        for (int a = 0; a < 12; ++a) {
            const float* src; float scl;
            if (a < 4)      { src = user  + (size_t)a       * (B_TOK * DMODEL); scl = 0.125f; }
            else if (a < 9) { src = genre + (size_t)(a - 4) * (B_TOK * DMODEL); scl = 1.0f;  }
            else            { src = mood  + (size_t)(a - 9) * (B_TOK * DMODEL); scl = 0.125f; }
            f32x4 v = *(const f32x4*)(src + src_off) * scl;
            f16x2 lo = pkrtz(v[0], v[1]);
            f16x2 hi = pkrtz(v[2], v[3]);
            f16x4 b = {lo[0], lo[1], hi[0], hi[1]};
            *(f16x4*)(smraw + a * 4096 + dst_off) = b;
        }
    }
    __syncthreads();

    // ---------------- per-wave weights ----------------
    ScoreW W;
    if constexpr (WSB) {
        load_scorew_pre(W, swf, b1fp, b2fp, (wv < 4) ? 0 : 1, lane);
    } else {
        if (wv < 4) load_scorew<false>(W, lw1, lb1, lw2, lb2, tl, g16);
        else        load_scorew<false>(W, sw1, sb1, sw2, sb2, tl, g16);
    }

    // waves 0-3: L pairs 5/5/5/5; waves 4-7: S pairs 4/4/4/3
    int pstart, pcount, sbase;
    if (wv < 4) { pstart = 5 * wv;       pcount = 5;                  sbase = 0; }
    else        { pstart = 4 * (wv - 4); pcount = (wv == 7) ? 3 : 4;  sbase = 9; }

    int aA = sbase + pstart / 5;
    int aB = 4 + pstart % 5;

    f16x8 attA0 = {0,0,0,0,0,0,0,0}, attA1 = {0,0,0,0,0,0,0,0};
    f16x8 attB0 = {0,0,0,0,0,0,0,0}, attB1 = {0,0,0,0,0,0,0,0};

    const unsigned char* lbase = smraw;
    const int rowbA = tl * 128;
    const int rowbB = (16 + tl) * 128;
    const int swz   = (tl & 7) << 4;
    const int ko2   = g16 * 16;
    const int o0 = ko2 ^ swz;
    const int o1 = (ko2 + 64) ^ swz;

    auto rd = [&](int arr, int rowb, int off) -> f16x8 {
        return *(const f16x8*)(lbase + arr * 4096 + rowb + off);
    };

    // software-pipelined pair loop
    f16x8 uA0 = rd(aA, rowbA, o0), uA1 = rd(aA, rowbA, o1);
    f16x8 uB0 = rd(aA, rowbB, o0), uB1 = rd(aA, rowbB, o1);
    f16x8 gA0 = rd(aB, rowbA, o0), gA1 = rd(aB, rowbA, o1);
    f16x8 gB0 = rd(aB, rowbB, o0), gB1 = rd(aB, rowbB, o1);

    for (int pi = 0; pi < pcount; ++pi) {
        f16x8 xaA0 = uA0 * gA0, xaA1 = uA1 * gA1;
        f16x8 xaB0 = uB0 * gB0, xaB1 = uB1 * gB1;

        f16x8 ngA0 = gA0, ngA1 = gA1, ngB0 = gB0, ngB1 = gB1;
        if (pi + 1 < pcount) {                 // wave-uniform branch
            int nB = aB + 1;
            if (nB == 9) {
                nB = 4; ++aA;
                uA0 = rd(aA, rowbA, o0); uA1 = rd(aA, rowbA, o1);
                uB0 = rd(aA, rowbB, o0); uB1 = rd(aA, rowbB, o1);
            }
            aB = nB;
            ngA0 = rd(aB, rowbA, o0); ngA1 = rd(aB, rowbA, o1);
            ngB0 = rd(aB, rowbB, o0); ngB1 = rd(aB, rowbB, o1);
        }

        f32x4 scA = score16<true>(W, xaA0, xaA1);
        f32x4 scB = score16<true>(W, xaB0, xaB1);

        _Float16 hA = (_Float16)scA[0];
        _Float16 hB = (_Float16)scB[0];
        f16x8 svA = {hA,hA,hA,hA,hA,hA,hA,hA};
        f16x8 svB = {hB,hB,hB,hB,hB,hB,hB,hB};
        attA0 += svA * xaA0;
        attA1 += svA * xaA1;
        attB0 += svB * xaB0;
        attB1 += svB * xaB1;

        gA0 = ngA0; gA1 = ngA1; gB0 = ngB0; gB1 = ngB1;
    }

    __syncthreads();   // all waves done READING inputs before overlay write

    // ---------------- write att partials (f16, overlay) ----------------
    *(f16x8*)(att + (wv * 32 + tl) * 80 + g16 * 8)           = attA0;
    *(f16x8*)(att + (wv * 32 + tl) * 80 + 32 + g16 * 8)      = attA1;
    *(f16x8*)(att + (wv * 32 + 16 + tl) * 80 + g16 * 8)      = attB0;
    *(f16x8*)(att + (wv * 32 + 16 + tl) * 80 + 32 + g16 * 8) = attB1;
    __syncthreads();

    // ---------------- gate scores rl / rs (exact exp2 path) -----------
    if (wv < 2) {
        ScoreW ZW;
        if constexpr (WSB) {
            load_scorew_pre(ZW, swf, b1fp, b2fp, (wv == 0) ? 2 : 3, lane);
        } else {
            if (wv == 0) load_scorew<true>(ZW, zlw1, zlb1, zlw2, zlb2, tl, g16);
            else         load_scorew<true>(ZW, zsw1, zsb1, zsw2, zsb2, tl, g16);
        }
        const int wb0 = wv * 4;   // wv0 sums L waves 0-3; wv1 sums S waves 4-7
        #pragma unroll
        for (int g = 0; g < 2; ++g) {
            const int r = g * 16 + tl;
            f16x8 za0 = *(const f16x8*)(att + ((wb0 + 0) * 32 + r) * 80 + g16 * 8)
                      + *(const f16x8*)(att + ((wb0 + 1) * 32 + r) * 80 + g16 * 8)
                      + *(const f16x8*)(att + ((wb0 + 2) * 32 + r) * 80 + g16 * 8)
                      + *(const f16x8*)(att + ((wb0 + 3) * 32 + r) * 80 + g16 * 8);
            f16x8 za1 = *(const f16x8*)(att + ((wb0 + 0) * 32 + r) * 80 + 32 + g16 * 8)
                      + *(const f16x8*)(att + ((wb0 + 1) * 32 + r) * 80 + 32 + g16 * 8)
                      + *(const f16x8*)(att + ((wb0 + 2) * 32 + r) * 80 + 32 + g16 * 8)
                      + *(const f16x8*)(att + ((wb0 + 3) * 32 + r) * 80 + 32 + g16 * 8);
            f32x4 rz = score16<false>(ZW, za0, za1);
            if (g16 == 0) rsc[wv * 32 + r] = rz[0];
        }
    }
    __syncthreads();

    // ---------------- mix + store (512 threads, one pass) -------------
    {
        const int r  = tid >> 4;             // 0..31
        const int k4 = (tid & 15) << 2;
        f16x4 Lh = {0,0,0,0}, Sh = {0,0,0,0};
        #pragma unroll
        for (int b = 0; b < 4; ++b) {
            Lh += *(const f16x4*)(att + ((b + 0) * 32 + r) * 80 + k4);
            Sh += *(const f16x4*)(att + ((b + 4) * 32 + r) * 80 + k4);
        }
        const float rl = rsc[r], rs = rsc[32 + r];
        const float r0 = __builtin_amdgcn_rcpf(1.0f + __builtin_amdgcn_exp2f((rs - rl) * L2E));
        float o[4];
        #pragma unroll
        for (int i = 0; i < 4; ++i) {
            const float Lf = (float)Lh[i], Sf = (float)Sh[i];
            o[i] = Sf + (Lf - Sf) * r0;
        }
        const size_t base = (size_t)wg * 2048 + (size_t)r * 64 + k4;
        if constexpr (WSB) {
            bf16x4 b = {f2bf(o[0]), f2bf(o[1]), f2bf(o[2]), f2bf(o[3])};
            *(bf16x4*)(bout + base) = b;
        } else {
            f32x4 mx = {o[0], o[1], o[2], o[3]};
            *(f32x4*)(fout + base) = mx;
        }
    }
}

// =====================================================================
// Kernel 0a: lin_w fp32 -> bf16 into workspace
// =====================================================================
__global__ __launch_bounds__(256) void conv_w(const float* __restrict__ w,
                                              short* __restrict__ o)
{
    const size_t i = ((size_t)blockIdx.x * 256 + threadIdx.x) * 4;
    f32x4 v = *(const f32x4*)(w + i);
    bf16x4 b;
    b[0] = f2bf(v[0]); b[1] = f2bf(v[1]); b[2] = f2bf(v[2]); b[3] = f2bf(v[3]);
    *(bf16x4*)(o + i) = b;
}

// =====================================================================
// Kernel 0b: score weights -> pre-permuted f16 fragments in ws.
// =====================================================================
__global__ __launch_bounds__(256) void conv_sw(
    const float* __restrict__ lw1,  const float* __restrict__ lb1,
    const float* __restrict__ lw2,  const float* __restrict__ lb2,
    const float* __restrict__ sw1,  const float* __restrict__ sb1,
    const float* __restrict__ sw2,  const float* __restrict__ sb2,
    const float* __restrict__ zlw1, const float* __restrict__ zlb1,
    const float* __restrict__ zlw2, const float* __restrict__ zlb2,
    const float* __restrict__ zsw1, const float* __restrict__ zsb1,
    const float* __restrict__ zsw2, const float* __restrict__ zsb2,
    _Float16* __restrict__ swf, float* __restrict__ b1f, float* __restrict__ b2f)
{
    const int blk = blockIdx.x, tid = threadIdx.x;
    if (blk < 80) {
        const int idx = blk * 256 + tid;          // 0..20479
        const int e = idx & 7;
        int t = idx >> 3;
        const int lane = t & 63; t >>= 6;
        const int f = t % 10;
        const int branch = t / 10;
        const int tl = lane & 15, g16 = lane >> 4;
        const float* w1p = (branch == 0) ? lw1 : (branch == 1) ? sw1 : (branch == 2) ? zlw1 : zsw1;
        const float* w2p = (branch == 0) ? lw2 : (branch == 1) ? sw2 : (branch == 2) ? zlw2 : zsw2;
        float val;
        if (f < 8) {
            const int nt = f >> 1, kk = f & 1;
            const int q = nt >> 1, hi = (nt & 1) * 4;
            const int j = q * 32 + (tl >> 2) * 8 + hi + (tl & 3);
            val = w1p[j * 64 + kk * 32 + g16 * 8 + e];
            if (branch >= 2) val *= NL2E;
        } else {
            const int q = f - 8;
            val = w2p[q * 32 + g16 * 8 + e];
        }
        swf[idx] = (_Float16)val;
    } else {
        const int idx = (blk - 80) * 256 + tid;   // 0..1023
        const int branch = idx >> 8, nt = (idx >> 6) & 3, lane = idx & 63;
        const int q = nt >> 1, hi = (nt & 1) * 4, g16 = lane >> 4;
        const float* b1p = (branch == 0) ? lb1 : (branch == 1) ? sb1 : (branch == 2) ? zlb1 : zsb1;
        const float scl = (branch >= 2) ? NL2E : 1.0f;
        #pragma unroll
        for (int c = 0; c < 4; ++c)
            b1f[idx * 4 + c] = b1p[q * 32 + g16 * 8 + hi + c] * scl;
        if (blk == 80 && tid < 4) {
            const float* b2p = (tid == 0) ? lb2 : (tid == 1) ? sb2 : (tid == 2) ? zlb2 : zsb2;
            b2f[tid] = b2p[0];
        }
    }
}

// =====================================================================
// Kernel 2 (ws path): C = mix_bf16 @ linw_bf16^T + linb.
// =====================================================================
__global__ __launch_bounds__(256, 2) void final_gemm_ws(
    const short* __restrict__ A, const short* __restrict__ Bw,
    const float* __restrict__ bias, float* __restrict__ C)
{
    __shared__ __attribute__((aligned(16))) short lA[64 * 64];
    __shared__ __attribute__((aligned(16))) short lB[128 * 64];

    const int tid  = threadIdx.x;
    const int lane = tid & 63;
    const int wv   = tid >> 6;
    const int tl   = lane & 15;
    const int g16  = lane >> 4;
    const int wr   = wv >> 1;
    const int wc   = wv & 1;
    const int bm   = blockIdx.x & 127;
    const int bn   = blockIdx.x >> 7;
    const int m0   = bm * 64, n0 = bn * 128;

    f32x4 acc[2][4];
    #pragma unroll
    for (int mt = 0; mt < 2; ++mt)
        #pragma unroll
        for (int nt = 0; nt < 4; ++nt) { f32x4 z = {0.f,0.f,0.f,0.f}; acc[mt][nt] = z; }

    bf16x8 ra[2], rb[4];
    auto LD = [&](int ks) {
        #pragma unroll
        for (int i = 0; i < 2; ++i) {
            const int c = tid + i * 256;
            ra[i] = *(const bf16x8*)(A + (size_t)(m0 + (c >> 3)) * 512 + ks * 64 + (c & 7) * 8);
        }
        #pragma unroll
        for (int i = 0; i < 4; ++i) {
            const int c = tid + i * 256;
            rb[i] = *(const bf16x8*)(Bw + (size_t)(n0 + (c >> 3)) * 512 + ks * 64 + (c & 7) * 8);
        }
    };

    LD(0);
    for (int ks = 0; ks < 8; ++ks) {
        __syncthreads();
        #pragma unroll
        for (int i = 0; i < 2; ++i) {
            const int c = tid + i * 256, row = c >> 3;
            *(bf16x8*)(lA + row * 64 + ((c & 7) ^ (row & 7)) * 8) = ra[i];
        }
        #pragma unroll
        for (int i = 0; i < 4; ++i) {
            const int c = tid + i * 256, row = c >> 3;
            *(bf16x8*)(lB + row * 64 + ((c & 7) ^ (row & 7)) * 8) = rb[i];
        }
        __syncthreads();
        if (ks < 7) LD(ks + 1);
        #pragma unroll
        for (int kk = 0; kk < 2; ++kk) {
            bf16x8 af[2], bfr[4];
            #pragma unroll
            for (int mt = 0; mt < 2; ++mt) {
                const int row = wr * 32 + mt * 16 + tl;
                af[mt] = *(const bf16x8*)(lA + row * 64 + ((kk * 4 + g16) ^ (row & 7)) * 8);
            }
            #pragma unroll
            for (int nt = 0; nt < 4; ++nt) {
                const int row = wc * 64 + nt * 16 + tl;
                bfr[nt] = *(const bf16x8*)(lB + row * 64 + ((kk * 4 + g16) ^ (row & 7)) * 8);
            }
            #pragma unroll
            for (int mt = 0; mt < 2; ++mt)
                #pragma unroll
                for (int nt = 0; nt < 4; ++nt)
                    acc[mt][nt] = __builtin_amdgcn_mfma_f32_16x16x32_bf16(af[mt], bfr[nt], acc[mt][nt], 0, 0, 0);
        }
    }

    #pragma unroll
    for (int nt = 0; nt < 4; ++nt) {
        const int n = n0 + wc * 64 + nt * 16 + tl;
        const float bv = bias[n];
        #pragma unroll
        for (int mt = 0; mt < 2; ++mt) {
            #pragma unroll
            for (int r = 0; r < 4; ++r) {
                C[(size_t)(m0 + wr * 32 + mt * 16 + g16 * 4 + r) * 512 + n] = acc[mt][nt][r] + bv;
            }
        }
    }
}

// =====================================================================
// Fallback (no ws): in-place GEMM on d_out
// =====================================================================
__global__ __launch_bounds__(256, 2) void final_gemm_ip(
    const float* __restrict__ linw, const float* __restrict__ linb, float* io)
{
    const int tid  = threadIdx.x;
    const int lane = tid & 63;
    const int wv   = tid >> 6;
    const int tl   = lane & 15;
    const int g16  = lane >> 4;
    const int row0 = blockIdx.x * 64 + wv * 16;

    f32x4 acc[32];
    #pragma unroll
    for (int nt = 0; nt < 32; ++nt) { f32x4 z = {0.f,0.f,0.f,0.f}; acc[nt] = z; }

    for (int ks = 0; ks < 16; ++ks) {
        const int k0 = ks * 32 + g16 * 8;
        const float* ar = io + (size_t)(row0 + tl) * 512 + k0;
        f32x4 a0 = *(const f32x4*)ar;
        f32x4 a1 = *(const f32x4*)(ar + 4);
        bf16x8 af;
        af[0]=f2bf(a0[0]); af[1]=f2bf(a0[1]); af[2]=f2bf(a0[2]); af[3]=f2bf(a0[3]);
        af[4]=f2bf(a1[0]); af[5]=f2bf(a1[1]); af[6]=f2bf(a1[2]); af[7]=f2bf(a1[3]);
        #pragma unroll
        for (int nt = 0; nt < 32; ++nt) {
            const int n = nt * 16 + tl;
            const float* br = linw + (size_t)n * 512 + k0;
            f32x4 b0 = *(const f32x4*)br;
            f32x4 b1 = *(const f32x4*)(br + 4);
            bf16x8 bv;
            bv[0]=f2bf(b0[0]); bv[1]=f2bf(b0[1]); bv[2]=f2bf(b0[2]); bv[3]=f2bf(b0[3]);
            bv[4]=f2bf(b1[0]); bv[5]=f2bf(b1[1]); bv[6]=f2bf(b1[2]); bv[7]=f2bf(b1[3]);
            acc[nt] = __builtin_amdgcn_mfma_f32_16x16x32_bf16(af, bv, acc[nt], 0, 0, 0);
        }
    }

    #pragma unroll
    for (int nt = 0; nt < 32; ++nt) {
        const int n = nt * 16 + tl;
        const float lb = linb[n];
        #pragma unroll
        for (int r = 0; r < 4; ++r)
            io[(size_t)(row0 + g16 * 4 + r) * 512 + n] = acc[nt][r] + lb;
    }
}

// =====================================================================
extern "C" void kernel_launch(void* const* d_in, const int* in_sizes, int n_in,
                              void* d_out, int out_size, void* d_ws, size_t ws_size,
                              hipStream_t stream)
{
    const float* user = (const float*)d_in[0];
    const float* mood = (const float*)d_in[1];
    const float* genre= (const float*)d_in[2];
    const float* lw1  = (const float*)d_in[3];
    const float* lb1  = (const float*)d_in[4];
    const float* lw2  = (const float*)d_in[5];
    const float* lb2  = (const float*)d_in[6];
    const float* sw1  = (const float*)d_in[7];
    const float* sb1  = (const float*)d_in[8];
    const float* sw2  = (const float*)d_in[9];
    const float* sb2  = (const float*)d_in[10];
    const float* zlw1 = (const float*)d_in[11];
    const float* zlb1 = (const float*)d_in[12];
    const float* zlw2 = (const float*)d_in[13];
    const float* zlb2 = (const float*)d_in[14];
    const float* zsw1 = (const float*)d_in[15];
    const float* zsb1 = (const float*)d_in[16];
    const float* zsw2 = (const float*)d_in[17];
    const float* zsb2 = (const float*)d_in[18];
    const float* linw = (const float*)d_in[19];
    const float* linb = (const float*)d_in[20];
    float* out = (float*)d_out;

    const size_t SWF_ELTS = (size_t)4 * 10 * 64 * 8;   // 20480 f16
    const size_t B1F_ELTS = (size_t)4 * 4 * 64 * 4;    // 4096 f32
    const size_t WNEED = (size_t)512 * 512 * 2 + (size_t)B_TOK * 512 * 2
                       + SWF_ELTS * 2 + (B1F_ELTS + 4) * 4;

    if (ws_size >= WNEED) {
        short*     wb   = (short*)d_ws;
        short*     mixb = wb + 512 * 512;
        _Float16*  swf  = (_Float16*)(mixb + (size_t)B_TOK * 512);
        float*     b1f  = (float*)(swf + SWF_ELTS);
        float*     b2f  = b1f + B1F_ELTS;

        conv_w<<<256, 256, 0, stream>>>(linw, wb);
        conv_sw<<<84, 256, 0, stream>>>(lw1, lb1, lw2, lb2, sw1, sb1, sw2, sb2,
                                        zlw1, zlb1, zlw2, zlb2, zsw1, zsb1, zsw2, zsb2,
                                        swf, b1f, b2f);
        fused_att<true><<<B_TOK / 4, 512, 0, stream>>>(
            user, mood, genre,
            lw1, lb1, lw2, lb2, sw1, sb1, sw2, sb2,
            zlw1, zlb1, zlw2, zlb2, zsw1, zsb1, zsw2, zsb2,
            swf, b1f, b2f, nullptr, mixb);
        final_gemm_ws<<<512, 256, 0, stream>>>(mixb, wb, linb, out);
    } else {
        fused_att<false><<<B_TOK / 4, 512, 0, stream>>>(
            user, mood, genre,
            lw1, lb1, lw2, lb2, sw1, sb1, sw2, sb2,
            zlw1, zlb1, zlw2, zlb2, zsw1, zsb1, zsw2, zsb2,
            nullptr, nullptr, nullptr, out, nullptr);
        final_gemm_ip<<<B_TOK / 64, 256, 0, stream>>>(linw, linb, out);
    }
}

// Round 14
// 70.860 us; speedup vs baseline: 5.3823x; 1.3431x over previous
//
#include <hip/hip_runtime.h>
#include <hip/hip_bf16.h>
#include <stdint.h>

#define B_TOK 8192
#define DMODEL 512

typedef __attribute__((ext_vector_type(4))) float f32x4;
typedef __attribute__((ext_vector_type(8))) short bf16x8;
typedef __attribute__((ext_vector_type(4))) short bf16x4;
typedef __attribute__((ext_vector_type(2))) _Float16 f16x2;
typedef __attribute__((ext_vector_type(4))) _Float16 f16x4;
typedef __attribute__((ext_vector_type(8))) _Float16 f16x8;

__device__ __forceinline__ short f2bf(float f) {
    union { float f; uint32_t u; } v; v.f = f;
    uint32_t r = (v.u + 0x7fffu + ((v.u >> 16) & 1u)) >> 16;
    return (short)r;
}

__device__ __forceinline__ f16x2 pkrtz(float a, float b) {
    auto r = __builtin_amdgcn_cvt_pkrtz(a, b);
    union { decltype(r) i; f16x2 o; } u; u.i = r;
    return u.o;
}

__device__ __forceinline__ float sigm2(float x) {   // x pre-scaled by -log2e
    return __builtin_amdgcn_rcpf(1.0f + __builtin_amdgcn_exp2f(x));
}

#define NL2E (-1.44269504089f)
#define L2E  (1.44269504089f)

__device__ __forceinline__ f16x8 ldh(const float* __restrict__ p, float scl) {
    f32x4 a0 = *(const f32x4*)p * scl;
    f32x4 a1 = *(const f32x4*)(p + 4) * scl;
    f16x2 p0 = pkrtz(a0[0], a0[1]);
    f16x2 p1 = pkrtz(a0[2], a0[3]);
    f16x2 p2 = pkrtz(a1[0], a1[1]);
    f16x2 p3 = pkrtz(a1[2], a1[3]);
    return (f16x8){p0[0],p0[1],p1[0],p1[1],p2[0],p2[1],p3[0],p3[1]};
}

// ---- score-head machinery (swapped-operand MFMA pipeline, r5-r10) ----
struct ScoreW {
    f16x8 w1f[4][2];
    f32x4 b1f[4];
    f16x8 w2f[2];
    f32x4 b2v;
};

// fallback (no-ws) loader: from f32 weights, permute + convert in-wave
template <bool EXPS>
__device__ __forceinline__ void load_scorew(ScoreW& W,
    const float* __restrict__ w1p, const float* __restrict__ b1p,
    const float* __restrict__ w2p, const float* __restrict__ b2p,
    int tl, int g16)
{
    const float scl = EXPS ? NL2E : 1.0f;
    #pragma unroll
    for (int nt = 0; nt < 4; ++nt) {
        const int q  = nt >> 1;
        const int hi = (nt & 1) * 4;
        const int j  = q * 32 + (tl >> 2) * 8 + hi + (tl & 3);
        #pragma unroll
        for (int kk = 0; kk < 2; ++kk)
            W.w1f[nt][kk] = ldh(w1p + j * 64 + kk * 32 + g16 * 8, scl);
        W.b1f[nt] = *(const f32x4*)(b1p + q * 32 + g16 * 8 + hi) * scl;
    }
    #pragma unroll
    for (int q = 0; q < 2; ++q)
        W.w2f[q] = ldh(w2p + q * 32 + g16 * 8, 1.0f);
    const float b2 = b2p[0];
    f32x4 bb = {b2, b2, b2, b2};
    W.b2v = bb;
}

// r11: pre-permuted f16 fragment loader. 10+4 fully-coalesced 16B loads,
// no converts, no permute arithmetic. swf layout: [branch][frag(10)][lane][8]
// b1f: [branch][nt][lane][4] f32 (pre-scaled); b2f: [branch] f32.
__device__ __forceinline__ void load_scorew_pre(ScoreW& W,
    const _Float16* __restrict__ swf, const float* __restrict__ b1fp,
    const float* __restrict__ b2fp, int branch, int lane)
{
    #pragma unroll
    for (int nt = 0; nt < 4; ++nt)
        #pragma unroll
        for (int kk = 0; kk < 2; ++kk)
            W.w1f[nt][kk] = *(const f16x8*)(swf + ((size_t)(branch * 10 + nt * 2 + kk) * 64 + lane) * 8);
    W.w2f[0] = *(const f16x8*)(swf + ((size_t)(branch * 10 + 8) * 64 + lane) * 8);
    W.w2f[1] = *(const f16x8*)(swf + ((size_t)(branch * 10 + 9) * 64 + lane) * 8);
    #pragma unroll
    for (int nt = 0; nt < 4; ++nt)
        W.b1f[nt] = *(const f32x4*)(b1fp + ((size_t)(branch * 4 + nt) * 64 + lane) * 4);
    const float b2 = b2fp[branch];
    f32x4 bb = {b2, b2, b2, b2};
    W.b2v = bb;
}

template <bool POLY>
__device__ __forceinline__ f32x4 score16(const ScoreW& W, f16x8 xa0, f16x8 xa1)
{
    f32x4 acc1[4];
    __builtin_amdgcn_s_setprio(1);                          // T5: favor MFMA wave
    #pragma unroll
    for (int nt = 0; nt < 4; ++nt)
        acc1[nt] = __builtin_amdgcn_mfma_f32_16x16x32_f16(W.w1f[nt][0], xa0, W.b1f[nt], 0, 0, 0);
    #pragma unroll
    for (int nt = 0; nt < 4; ++nt)
        acc1[nt] = __builtin_amdgcn_mfma_f32_16x16x32_f16(W.w1f[nt][1], xa1, acc1[nt], 0, 0, 0);
    __builtin_amdgcn_s_setprio(0);

    f32x4 acc2a = W.b2v;
    f32x4 acc2b = {0.f, 0.f, 0.f, 0.f};
    #pragma unroll
    for (int q = 0; q < 2; ++q) {
        f16x8 sb;
        if constexpr (POLY) {
            const _Float16 c1 = (_Float16)0.25f;
            const _Float16 c2 = (_Float16)(-0.0208333f);
            const _Float16 c3 = (_Float16)0.00208333f;
            const _Float16 hf = (_Float16)0.5f;
            f16x2 h0 = pkrtz(acc1[2*q][0],   acc1[2*q][1]);
            f16x2 h1 = pkrtz(acc1[2*q][2],   acc1[2*q][3]);
            f16x2 h2 = pkrtz(acc1[2*q+1][0], acc1[2*q+1][1]);
            f16x2 h3 = pkrtz(acc1[2*q+1][2], acc1[2*q+1][3]);
            f16x8 hv = {h0[0],h0[1],h1[0],h1[1],h2[0],h2[1],h3[0],h3[1]};
            f16x8 C1 = {c1,c1,c1,c1,c1,c1,c1,c1};
            f16x8 C2 = {c2,c2,c2,c2,c2,c2,c2,c2};
            f16x8 C3 = {c3,c3,c3,c3,c3,c3,c3,c3};
            f16x8 HF = {hf,hf,hf,hf,hf,hf,hf,hf};
            f16x8 hh = hv * hv;
            f16x8 u  = hh * C3 + C2;
            f16x8 v  = hh * u  + C1;
            sb       = hv * v  + HF;
        } else {
            f16x2 s0 = pkrtz(sigm2(acc1[2*q][0]),   sigm2(acc1[2*q][1]));
            f16x2 s1 = pkrtz(sigm2(acc1[2*q][2]),   sigm2(acc1[2*q][3]));
            f16x2 s2 = pkrtz(sigm2(acc1[2*q+1][0]), sigm2(acc1[2*q+1][1]));
            f16x2 s3 = pkrtz(sigm2(acc1[2*q+1][2]), sigm2(acc1[2*q+1][3]));
            sb = (f16x8){s0[0],s0[1],s1[0],s1[1],s2[0],s2[1],s3[0],s3[1]};
        }
        __builtin_amdgcn_s_setprio(1);
        if (q == 0)
            acc2a = __builtin_amdgcn_mfma_f32_16x16x32_f16(W.w2f[0], sb, acc2a, 0, 0, 0);
        else
            acc2b = __builtin_amdgcn_mfma_f32_16x16x32_f16(W.w2f[1], sb, acc2b, 0, 0, 0);
        __builtin_amdgcn_s_setprio(0);
    }
    return acc2a + acc2b;
}

// =====================================================================
// Kernel 1 (r14 = r11 best-known): 4 waves = 4 tokens, 2 row-groups per
// wave, LDS-staged f16 inputs, software-pipelined pair loop, poly
// sigmoid, pre-permuted weights from ws, setprio around MFMA.
// r13 verdict: 8-wave split clean-negative (3rd strike) -> revert.
// =====================================================================
template <bool WSB>
__global__ __launch_bounds__(256, 3) void fused_att(
    const float* __restrict__ user, const float* __restrict__ mood,
    const float* __restrict__ genre,
    const float* __restrict__ lw1,  const float* __restrict__ lb1,
    const float* __restrict__ lw2,  const float* __restrict__ lb2,
    const float* __restrict__ sw1,  const float* __restrict__ sb1,
    const float* __restrict__ sw2,  const float* __restrict__ sb2,
    const float* __restrict__ zlw1, const float* __restrict__ zlb1,
    const float* __restrict__ zlw2, const float* __restrict__ zlb2,
    const float* __restrict__ zsw1, const float* __restrict__ zsb1,
    const float* __restrict__ zsw2, const float* __restrict__ zsb2,
    const _Float16* __restrict__ swf, const float* __restrict__ b1fp,
    const float* __restrict__ b2fp,
    float* __restrict__ fout, short* __restrict__ bout)
{
    __shared__ __attribute__((aligned(16))) unsigned char smraw[12 * 32 * 128];
    _Float16* att = (_Float16*)smraw;              // [4][32][80]
    float*    rsc = (float*)(smraw + 20480);       // [2][32]

    const int tid  = threadIdx.x;
    const int lane = tid & 63;
    const int wv   = tid >> 6;    // 0..3
    const int tl   = lane & 15;
    const int g16  = lane >> 4;
    const int wg   = blockIdx.x;  // tokens [4*wg, 4*wg+4)

    // ---------------- stage inputs fp32 -> f16 LDS ----------------
    {
        const int k4 = (tid & 15) << 2;
        #pragma unroll
        for (int h = 0; h < 2; ++h) {
            const int r = h * 16 + (tid >> 4);
            const int dst_off = r * 128 + ((k4 * 2) ^ ((r & 7) << 4));
            const size_t src_off = (size_t)wg * 2048 + (size_t)r * 64 + k4;
            #pragma unroll
            for (int a = 0; a < 12; ++a) {
                const float* src; float scl;
                if (a < 4)      { src = user  + (size_t)a       * (B_TOK * DMODEL); scl = 0.125f; }
                else if (a < 9) { src = genre + (size_t)(a - 4) * (B_TOK * DMODEL); scl = 1.0f;  }
                else            { src = mood  + (size_t)(a - 9) * (B_TOK * DMODEL); scl = 0.125f; }
                f32x4 v = *(const f32x4*)(src + src_off) * scl;
                f16x2 lo = pkrtz(v[0], v[1]);
                f16x2 hi = pkrtz(v[2], v[3]);
                f16x4 b = {lo[0], lo[1], hi[0], hi[1]};
                *(f16x4*)(smraw + a * 4096 + dst_off) = b;
            }
        }
    }
    __syncthreads();

    // ---------------- per-wave weights ----------------
    ScoreW W;
    if constexpr (WSB) {
        load_scorew_pre(W, swf, b1fp, b2fp, (wv < 2) ? 0 : 1, lane);
    } else {
        if (wv < 2) load_scorew<false>(W, lw1, lb1, lw2, lb2, tl, g16);
        else        load_scorew<false>(W, sw1, sb1, sw2, sb2, tl, g16);
    }

    int pcount, sbase, pstart;
    if      (wv == 0) { pstart = 0;  pcount = 10; sbase = 0; }
    else if (wv == 1) { pstart = 10; pcount = 10; sbase = 0; }
    else if (wv == 2) { pstart = 0;  pcount = 8;  sbase = 9; }
    else              { pstart = 8;  pcount = 7;  sbase = 9; }

    int aA = sbase + pstart / 5;
    int aB = 4 + pstart % 5;

    f16x8 attA0 = {0,0,0,0,0,0,0,0}, attA1 = {0,0,0,0,0,0,0,0};
    f16x8 attB0 = {0,0,0,0,0,0,0,0}, attB1 = {0,0,0,0,0,0,0,0};

    const unsigned char* lbase = smraw;
    const int rowbA = tl * 128;
    const int rowbB = (16 + tl) * 128;
    const int swz   = (tl & 7) << 4;
    const int ko2   = g16 * 16;
    const int o0 = ko2 ^ swz;
    const int o1 = (ko2 + 64) ^ swz;

    auto rd = [&](int arr, int rowb, int off) -> f16x8 {
        return *(const f16x8*)(lbase + arr * 4096 + rowb + off);
    };

    // software-pipelined pair loop: current frags in registers; next pair's
    // g (and boundary u) reads issued BEFORE the score dep-chain.
    f16x8 uA0 = rd(aA, rowbA, o0), uA1 = rd(aA, rowbA, o1);
    f16x8 uB0 = rd(aA, rowbB, o0), uB1 = rd(aA, rowbB, o1);
    f16x8 gA0 = rd(aB, rowbA, o0), gA1 = rd(aB, rowbA, o1);
    f16x8 gB0 = rd(aB, rowbB, o0), gB1 = rd(aB, rowbB, o1);

    for (int pi = 0; pi < pcount; ++pi) {
        f16x8 xaA0 = uA0 * gA0, xaA1 = uA1 * gA1;
        f16x8 xaB0 = uB0 * gB0, xaB1 = uB1 * gB1;

        f16x8 ngA0 = gA0, ngA1 = gA1, ngB0 = gB0, ngB1 = gB1;
        if (pi + 1 < pcount) {                 // wave-uniform branch
            int nB = aB + 1;
            if (nB == 9) {
                nB = 4; ++aA;
                uA0 = rd(aA, rowbA, o0); uA1 = rd(aA, rowbA, o1);
                uB0 = rd(aA, rowbB, o0); uB1 = rd(aA, rowbB, o1);
            }
            aB = nB;
            ngA0 = rd(aB, rowbA, o0); ngA1 = rd(aB, rowbA, o1);
            ngB0 = rd(aB, rowbB, o0); ngB1 = rd(aB, rowbB, o1);
        }

        f32x4 scA = score16<true>(W, xaA0, xaA1);
        f32x4 scB = score16<true>(W, xaB0, xaB1);

        _Float16 hA = (_Float16)scA[0];
        _Float16 hB = (_Float16)scB[0];
        f16x8 svA = {hA,hA,hA,hA,hA,hA,hA,hA};
        f16x8 svB = {hB,hB,hB,hB,hB,hB,hB,hB};
        attA0 += svA * xaA0;
        attA1 += svA * xaA1;
        attB0 += svB * xaB0;
        attB1 += svB * xaB1;

        gA0 = ngA0; gA1 = ngA1; gB0 = ngB0; gB1 = ngB1;
    }

    __syncthreads();   // all waves done READING inputs before overlay write

    // ---------------- write att partials (f16, overlay) ----------------
    *(f16x8*)(att + (wv * 32 + tl) * 80 + g16 * 8)           = attA0;
    *(f16x8*)(att + (wv * 32 + tl) * 80 + 32 + g16 * 8)      = attA1;
    *(f16x8*)(att + (wv * 32 + 16 + tl) * 80 + g16 * 8)      = attB0;
    *(f16x8*)(att + (wv * 32 + 16 + tl) * 80 + 32 + g16 * 8) = attB1;
    __syncthreads();

    // ---------------- gate scores rl / rs (exact exp2 path) -----------
    if (wv < 2) {
        ScoreW ZW;
        if constexpr (WSB) {
            load_scorew_pre(ZW, swf, b1fp, b2fp, (wv == 0) ? 2 : 3, lane);
        } else {
            if (wv == 0) load_scorew<true>(ZW, zlw1, zlb1, zlw2, zlb2, tl, g16);
            else         load_scorew<true>(ZW, zsw1, zsb1, zsw2, zsb2, tl, g16);
        }
        const int b0 = wv * 2, b1i = wv * 2 + 1;
        #pragma unroll
        for (int g = 0; g < 2; ++g) {
            const int r = g * 16 + tl;
            f16x8 za0 = *(const f16x8*)(att + (b0  * 32 + r) * 80 + g16 * 8) +
                        *(const f16x8*)(att + (b1i * 32 + r) * 80 + g16 * 8);
            f16x8 za1 = *(const f16x8*)(att + (b0  * 32 + r) * 80 + 32 + g16 * 8) +
                        *(const f16x8*)(att + (b1i * 32 + r) * 80 + 32 + g16 * 8);
            f32x4 rz = score16<false>(ZW, za0, za1);
            if (g16 == 0) rsc[wv * 32 + r] = rz[0];
        }
    }
    __syncthreads();

    // ---------------- mix + store ----------------
    {
        const int k4 = (tid & 15) << 2;
        #pragma unroll
        for (int h = 0; h < 2; ++h) {
            const int r = h * 16 + (tid >> 4);
            f16x4 Lh = *(const f16x4*)(att + (0 * 32 + r) * 80 + k4) +
                       *(const f16x4*)(att + (1 * 32 + r) * 80 + k4);
            f16x4 Sh = *(const f16x4*)(att + (2 * 32 + r) * 80 + k4) +
                       *(const f16x4*)(att + (3 * 32 + r) * 80 + k4);
            const float rl = rsc[r], rs = rsc[32 + r];
            const float r0 = __builtin_amdgcn_rcpf(1.0f + __builtin_amdgcn_exp2f((rs - rl) * L2E));
            float o[4];
            #pragma unroll
            for (int i = 0; i < 4; ++i) {
                const float Lf = (float)Lh[i], Sf = (float)Sh[i];
                o[i] = Sf + (Lf - Sf) * r0;
            }
            const size_t base = (size_t)wg * 2048 + (size_t)r * 64 + k4;
            if constexpr (WSB) {
                bf16x4 b = {f2bf(o[0]), f2bf(o[1]), f2bf(o[2]), f2bf(o[3])};
                *(bf16x4*)(bout + base) = b;
            } else {
                f32x4 mx = {o[0], o[1], o[2], o[3]};
                *(f32x4*)(fout + base) = mx;
            }
        }
    }
}

// =====================================================================
// Kernel 0a: lin_w fp32 -> bf16 into workspace
// =====================================================================
__global__ __launch_bounds__(256) void conv_w(const float* __restrict__ w,
                                              short* __restrict__ o)
{
    const size_t i = ((size_t)blockIdx.x * 256 + threadIdx.x) * 4;
    f32x4 v = *(const f32x4*)(w + i);
    bf16x4 b;
    b[0] = f2bf(v[0]); b[1] = f2bf(v[1]); b[2] = f2bf(v[2]); b[3] = f2bf(v[3]);
    *(bf16x4*)(o + i) = b;
}

// =====================================================================
// Kernel 0b: score weights -> pre-permuted f16 fragments in ws.
// swf[branch][frag 0..9][lane][8] f16; b1f[branch][nt][lane][4] f32;
// b2f[branch] f32. branch: 0=L,1=S (unscaled), 2=ZL,3=ZS (w1/b1 * -log2e).
// =====================================================================
__global__ __launch_bounds__(256) void conv_sw(
    const float* __restrict__ lw1,  const float* __restrict__ lb1,
    const float* __restrict__ lw2,  const float* __restrict__ lb2,
    const float* __restrict__ sw1,  const float* __restrict__ sb1,
    const float* __restrict__ sw2,  const float* __restrict__ sb2,
    const float* __restrict__ zlw1, const float* __restrict__ zlb1,
    const float* __restrict__ zlw2, const float* __restrict__ zlb2,
    const float* __restrict__ zsw1, const float* __restrict__ zsb1,
    const float* __restrict__ zsw2, const float* __restrict__ zsb2,
    _Float16* __restrict__ swf, float* __restrict__ b1f, float* __restrict__ b2f)
{
    const int blk = blockIdx.x, tid = threadIdx.x;
    if (blk < 80) {
        const int idx = blk * 256 + tid;          // 0..20479
        const int e = idx & 7;
        int t = idx >> 3;
        const int lane = t & 63; t >>= 6;
        const int f = t % 10;
        const int branch = t / 10;
        const int tl = lane & 15, g16 = lane >> 4;
        const float* w1p = (branch == 0) ? lw1 : (branch == 1) ? sw1 : (branch == 2) ? zlw1 : zsw1;
        const float* w2p = (branch == 0) ? lw2 : (branch == 1) ? sw2 : (branch == 2) ? zlw2 : zsw2;
        float val;
        if (f < 8) {
            const int nt = f >> 1, kk = f & 1;
            const int q = nt >> 1, hi = (nt & 1) * 4;
            const int j = q * 32 + (tl >> 2) * 8 + hi + (tl & 3);
            val = w1p[j * 64 + kk * 32 + g16 * 8 + e];
            if (branch >= 2) val *= NL2E;
        } else {
            const int q = f - 8;
            val = w2p[q * 32 + g16 * 8 + e];
        }
        swf[idx] = (_Float16)val;
    } else {
        const int idx = (blk - 80) * 256 + tid;   // 0..1023
        const int branch = idx >> 8, nt = (idx >> 6) & 3, lane = idx & 63;
        const int q = nt >> 1, hi = (nt & 1) * 4, g16 = lane >> 4;
        const float* b1p = (branch == 0) ? lb1 : (branch == 1) ? sb1 : (branch == 2) ? zlb1 : zsb1;
        const float scl = (branch >= 2) ? NL2E : 1.0f;
        #pragma unroll
        for (int c = 0; c < 4; ++c)
            b1f[idx * 4 + c] = b1p[q * 32 + g16 * 8 + hi + c] * scl;
        if (blk == 80 && tid < 4) {
            const float* b2p = (tid == 0) ? lb2 : (tid == 1) ? sb2 : (tid == 2) ? zlb2 : zsb2;
            b2f[tid] = b2p[0];
        }
    }
}

// =====================================================================
// Kernel 2 (ws path): C = mix_bf16 @ linw_bf16^T + linb.
// 64x128 tiles, 512 blocks, reg-prefetch + XOR-swizzled LDS.
// =====================================================================
__global__ __launch_bounds__(256, 2) void final_gemm_ws(
    const short* __restrict__ A, const short* __restrict__ Bw,
    const float* __restrict__ bias, float* __restrict__ C)
{
    __shared__ __attribute__((aligned(16))) short lA[64 * 64];
    __shared__ __attribute__((aligned(16))) short lB[128 * 64];

    const int tid  = threadIdx.x;
    const int lane = tid & 63;
    const int wv   = tid >> 6;
    const int tl   = lane & 15;
    const int g16  = lane >> 4;
    const int wr   = wv >> 1;
    const int wc   = wv & 1;
    const int bm   = blockIdx.x & 127;
    const int bn   = blockIdx.x >> 7;
    const int m0   = bm * 64, n0 = bn * 128;

    f32x4 acc[2][4];
    #pragma unroll
    for (int mt = 0; mt < 2; ++mt)
        #pragma unroll
        for (int nt = 0; nt < 4; ++nt) { f32x4 z = {0.f,0.f,0.f,0.f}; acc[mt][nt] = z; }

    bf16x8 ra[2], rb[4];
    auto LD = [&](int ks) {
        #pragma unroll
        for (int i = 0; i < 2; ++i) {
            const int c = tid + i * 256;
            ra[i] = *(const bf16x8*)(A + (size_t)(m0 + (c >> 3)) * 512 + ks * 64 + (c & 7) * 8);
        }
        #pragma unroll
        for (int i = 0; i < 4; ++i) {
            const int c = tid + i * 256;
            rb[i] = *(const bf16x8*)(Bw + (size_t)(n0 + (c >> 3)) * 512 + ks * 64 + (c & 7) * 8);
        }
    };

    LD(0);
    for (int ks = 0; ks < 8; ++ks) {
        __syncthreads();
        #pragma unroll
        for (int i = 0; i < 2; ++i) {
            const int c = tid + i * 256, row = c >> 3;
            *(bf16x8*)(lA + row * 64 + ((c & 7) ^ (row & 7)) * 8) = ra[i];
        }
        #pragma unroll
        for (int i = 0; i < 4; ++i) {
            const int c = tid + i * 256, row = c >> 3;
            *(bf16x8*)(lB + row * 64 + ((c & 7) ^ (row & 7)) * 8) = rb[i];
        }
        __syncthreads();
        if (ks < 7) LD(ks + 1);
        #pragma unroll
        for (int kk = 0; kk < 2; ++kk) {
            bf16x8 af[2], bfr[4];
            #pragma unroll
            for (int mt = 0; mt < 2; ++mt) {
                const int row = wr * 32 + mt * 16 + tl;
                af[mt] = *(const bf16x8*)(lA + row * 64 + ((kk * 4 + g16) ^ (row & 7)) * 8);
            }
            #pragma unroll
            for (int nt = 0; nt < 4; ++nt) {
                const int row = wc * 64 + nt * 16 + tl;
                bfr[nt] = *(const bf16x8*)(lB + row * 64 + ((kk * 4 + g16) ^ (row & 7)) * 8);
            }
            #pragma unroll
            for (int mt = 0; mt < 2; ++mt)
                #pragma unroll
                for (int nt = 0; nt < 4; ++nt)
                    acc[mt][nt] = __builtin_amdgcn_mfma_f32_16x16x32_bf16(af[mt], bfr[nt], acc[mt][nt], 0, 0, 0);
        }
    }

    #pragma unroll
    for (int nt = 0; nt < 4; ++nt) {
        const int n = n0 + wc * 64 + nt * 16 + tl;
        const float bv = bias[n];
        #pragma unroll
        for (int mt = 0; mt < 2; ++mt) {
            #pragma unroll
            for (int r = 0; r < 4; ++r) {
                C[(size_t)(m0 + wr * 32 + mt * 16 + g16 * 4 + r) * 512 + n] = acc[mt][nt][r] + bv;
            }
        }
    }
}

// =====================================================================
// Fallback (no ws): in-place GEMM on d_out
// =====================================================================
__global__ __launch_bounds__(256, 2) void final_gemm_ip(
    const float* __restrict__ linw, const float* __restrict__ linb, float* io)
{
    const int tid  = threadIdx.x;
    const int lane = tid & 63;
    const int wv   = tid >> 6;
    const int tl   = lane & 15;
    const int g16  = lane >> 4;
    const int row0 = blockIdx.x * 64 + wv * 16;

    f32x4 acc[32];
    #pragma unroll
    for (int nt = 0; nt < 32; ++nt) { f32x4 z = {0.f,0.f,0.f,0.f}; acc[nt] = z; }

    for (int ks = 0; ks < 16; ++ks) {
        const int k0 = ks * 32 + g16 * 8;
        const float* ar = io + (size_t)(row0 + tl) * 512 + k0;
        f32x4 a0 = *(const f32x4*)ar;
        f32x4 a1 = *(const f32x4*)(ar + 4);
        bf16x8 af;
        af[0]=f2bf(a0[0]); af[1]=f2bf(a0[1]); af[2]=f2bf(a0[2]); af[3]=f2bf(a0[3]);
        af[4]=f2bf(a1[0]); af[5]=f2bf(a1[1]); af[6]=f2bf(a1[2]); af[7]=f2bf(a1[3]);
        #pragma unroll
        for (int nt = 0; nt < 32; ++nt) {
            const int n = nt * 16 + tl;
            const float* br = linw + (size_t)n * 512 + k0;
            f32x4 b0 = *(const f32x4*)br;
            f32x4 b1 = *(const f32x4*)(br + 4);
            bf16x8 bv;
            bv[0]=f2bf(b0[0]); bv[1]=f2bf(b0[1]); bv[2]=f2bf(b0[2]); bv[3]=f2bf(b0[3]);
            bv[4]=f2bf(b1[0]); bv[5]=f2bf(b1[1]); bv[6]=f2bf(b1[2]); bv[7]=f2bf(b1[3]);
            acc[nt] = __builtin_amdgcn_mfma_f32_16x16x32_bf16(af, bv, acc[nt], 0, 0, 0);
        }
    }

    #pragma unroll
    for (int nt = 0; nt < 32; ++nt) {
        const int n = nt * 16 + tl;
        const float lb = linb[n];
        #pragma unroll
        for (int r = 0; r < 4; ++r)
            io[(size_t)(row0 + g16 * 4 + r) * 512 + n] = acc[nt][r] + lb;
    }
}

// =====================================================================
extern "C" void kernel_launch(void* const* d_in, const int* in_sizes, int n_in,
                              void* d_out, int out_size, void* d_ws, size_t ws_size,
                              hipStream_t stream)
{
    const float* user = (const float*)d_in[0];
    const float* mood = (const float*)d_in[1];
    const float* genre= (const float*)d_in[2];
    const float* lw1  = (const float*)d_in[3];
    const float* lb1  = (const float*)d_in[4];
    const float* lw2  = (const float*)d_in[5];
    const float* lb2  = (const float*)d_in[6];
    const float* sw1  = (const float*)d_in[7];
    const float* sb1  = (const float*)d_in[8];
    const float* sw2  = (const float*)d_in[9];
    const float* sb2  = (const float*)d_in[10];
    const float* zlw1 = (const float*)d_in[11];
    const float* zlb1 = (const float*)d_in[12];
    const float* zlw2 = (const float*)d_in[13];
    const float* zlb2 = (const float*)d_in[14];
    const float* zsw1 = (const float*)d_in[15];
    const float* zsb1 = (const float*)d_in[16];
    const float* zsw2 = (const float*)d_in[17];
    const float* zsb2 = (const float*)d_in[18];
    const float* linw = (const float*)d_in[19];
    const float* linb = (const float*)d_in[20];
    float* out = (float*)d_out;

    const size_t SWF_ELTS = (size_t)4 * 10 * 64 * 8;   // 20480 f16
    const size_t B1F_ELTS = (size_t)4 * 4 * 64 * 4;    // 4096 f32
    const size_t WNEED = (size_t)512 * 512 * 2 + (size_t)B_TOK * 512 * 2
                       + SWF_ELTS * 2 + (B1F_ELTS + 4) * 4;

    if (ws_size >= WNEED) {
        short*     wb   = (short*)d_ws;
        short*     mixb = wb + 512 * 512;
        _Float16*  swf  = (_Float16*)(mixb + (size_t)B_TOK * 512);
        float*     b1f  = (float*)(swf + SWF_ELTS);
        float*     b2f  = b1f + B1F_ELTS;

        conv_w<<<256, 256, 0, stream>>>(linw, wb);
        conv_sw<<<84, 256, 0, stream>>>(lw1, lb1, lw2, lb2, sw1, sb1, sw2, sb2,
                                        zlw1, zlb1, zlw2, zlb2, zsw1, zsb1, zsw2, zsb2,
                                        swf, b1f, b2f);
        fused_att<true><<<B_TOK / 4, 256, 0, stream>>>(
            user, mood, genre,
            lw1, lb1, lw2, lb2, sw1, sb1, sw2, sb2,
            zlw1, zlb1, zlw2, zlb2, zsw1, zsb1, zsw2, zsb2,
            swf, b1f, b2f, nullptr, mixb);
        final_gemm_ws<<<512, 256, 0, stream>>>(mixb, wb, linb, out);
    } else {
        fused_att<false><<<B_TOK / 4, 256, 0, stream>>>(
            user, mood, genre,
            lw1, lb1, lw2, lb2, sw1, sb1, sw2, sb2,
            zlw1, zlb1, zlw2, zlb2, zsw1, zsb1, zsw2, zsb2,
            nullptr, nullptr, nullptr, out, nullptr);
        final_gemm_ip<<<B_TOK / 64, 256, 0, stream>>>(linw, linb, out);
    }
}